// Round 5
// baseline (126.845 us; speedup 1.0000x reference)
//
#include <hip/hip_runtime.h>

#define Bv 4
#define Vv 50000
#define Cv 160

typedef float v2f __attribute__((ext_vector_type(2)));

// Kernel 1: per-(b,c) affine table A[b][c][12]:
//   A[0..8]  = R row-major (rows b1,b2,b3)
//   A[9..11] = center + V_nodes - R*center
// so out[b,v,:] = M·x_v + t with [M|t] = sum_c W[v,c]*A[b,c,:]
__global__ void precompute_A(const float* __restrict__ X,
                             const float* __restrict__ Vn,
                             const float* __restrict__ r6,
                             const int* __restrict__ idx,
                             float* __restrict__ A) {
    int i = blockIdx.x * blockDim.x + threadIdx.x;
    if (i >= Bv * Cv) return;
    int b = i / Cv, c = i % Cv;

    const float* d6 = r6 + (size_t)(b * Cv + c) * 6;
    float a1x = d6[0], a1y = d6[1], a1z = d6[2];
    float a2x = d6[3], a2y = d6[4], a2z = d6[5];

    float n1 = fmaxf(sqrtf(a1x*a1x + a1y*a1y + a1z*a1z), 1e-8f);
    float b1x = a1x / n1, b1y = a1y / n1, b1z = a1z / n1;

    float d = b1x*a2x + b1y*a2y + b1z*a2z;
    float px = a2x - d*b1x, py = a2y - d*b1y, pz = a2z - d*b1z;
    float n2 = fmaxf(sqrtf(px*px + py*py + pz*pz), 1e-8f);
    float b2x = px / n2, b2y = py / n2, b2z = pz / n2;

    float b3x = b1y*b2z - b1z*b2y;
    float b3y = b1z*b2x - b1x*b2z;
    float b3z = b1x*b2y - b1y*b2x;

    int iv = idx[c];
    const float* xc = X + ((size_t)b * Vv + iv) * 3;
    float cx = xc[0], cy = xc[1], cz = xc[2];
    const float* vn = Vn + (size_t)(b * Cv + c) * 3;
    float vx = vn[0], vy = vn[1], vz = vn[2];

    float* Ao = A + (size_t)(b * Cv + c) * 12;
    Ao[0] = b1x; Ao[1] = b1y; Ao[2] = b1z;
    Ao[3] = b2x; Ao[4] = b2y; Ao[5] = b2z;
    Ao[6] = b3x; Ao[7] = b3y; Ao[8] = b3z;
    Ao[9]  = cx + vx - (b1x*cx + b1y*cy + b1z*cz);
    Ao[10] = cy + vy - (b2x*cx + b2y*cy + b2z*cz);
    Ao[11] = cz + vz - (b3x*cx + b3y*cy + b3z*cz);
}

// Kernel 2: block = 256 threads = 4 waves; wave w -> batch b=w; each lane
// handles TWO vertices (v0+lane, v0+64+lane). Accumulators are float2
// {vertA, vertB} -> v_pk_fma_f32 (2 FMA/lane/instr). All loads on the
// vector path (vmcnt FIFO): b is NOT readfirstlane'd so A stays a vector
// (L1-broadcast) load, never an out-of-order s_load.
__global__ __launch_bounds__(256) void deform_main(const float* __restrict__ X,
                                                   const float* __restrict__ W,
                                                   const float* __restrict__ A,
                                                   float* __restrict__ out) {
    const int tid  = threadIdx.x;
    const int lane = tid & 63;
    const int b    = tid >> 6;            // uniform in fact, divergent to compiler
    const int v0   = blockIdx.x * 128;
    const int vA   = v0 + lane;
    const int vB   = v0 + 64 + lane;
    const bool validA = (vA < Vv);
    const bool validB = (vB < Vv);
    const int vcA = validA ? vA : (Vv - 1);
    const int vcB = validB ? vB : (Vv - 1);

    const float4* __restrict__ WrowA = (const float4*)(W + (size_t)vcA * Cv);
    const float4* __restrict__ WrowB = (const float4*)(W + (size_t)vcB * Cv);
    const float4* __restrict__ A4    = (const float4*)(A + (size_t)b * Cv * 12);

    const float* xpA = X + ((size_t)b * Vv + vcA) * 3;
    const float* xpB = X + ((size_t)b * Vv + vcB) * 3;
    float xA0 = xpA[0], xA1 = xpA[1], xA2 = xpA[2];
    float xB0 = xpB[0], xB1 = xpB[1], xB2 = xpB[2];

    v2f acc[12];
#pragma unroll
    for (int j = 0; j < 12; ++j) acc[j] = (v2f){0.0f, 0.0f};

#pragma unroll 2
    for (int c4 = 0; c4 < Cv / 4; ++c4) {
        float4 wqA = WrowA[c4];
        float4 wqB = WrowB[c4];
        const float wjA[4] = {wqA.x, wqA.y, wqA.z, wqA.w};
        const float wjB[4] = {wqB.x, wqB.y, wqB.z, wqB.w};
#pragma unroll
        for (int j = 0; j < 4; ++j) {
            int c = c4 * 4 + j;
            float4 a0 = A4[c * 3 + 0];   // M00 M01 M02 M10
            float4 a1 = A4[c * 3 + 1];   // M11 M12 M20 M21
            float4 a2 = A4[c * 3 + 2];   // M22 T0  T1  T2
            v2f w = (v2f){wjA[j], wjB[j]};
            acc[0]  = __builtin_elementwise_fma(w, (v2f){a0.x, a0.x}, acc[0]);
            acc[1]  = __builtin_elementwise_fma(w, (v2f){a0.y, a0.y}, acc[1]);
            acc[2]  = __builtin_elementwise_fma(w, (v2f){a0.z, a0.z}, acc[2]);
            acc[3]  = __builtin_elementwise_fma(w, (v2f){a0.w, a0.w}, acc[3]);
            acc[4]  = __builtin_elementwise_fma(w, (v2f){a1.x, a1.x}, acc[4]);
            acc[5]  = __builtin_elementwise_fma(w, (v2f){a1.y, a1.y}, acc[5]);
            acc[6]  = __builtin_elementwise_fma(w, (v2f){a1.z, a1.z}, acc[6]);
            acc[7]  = __builtin_elementwise_fma(w, (v2f){a1.w, a1.w}, acc[7]);
            acc[8]  = __builtin_elementwise_fma(w, (v2f){a2.x, a2.x}, acc[8]);
            acc[9]  = __builtin_elementwise_fma(w, (v2f){a2.y, a2.y}, acc[9]);
            acc[10] = __builtin_elementwise_fma(w, (v2f){a2.z, a2.z}, acc[10]);
            acc[11] = __builtin_elementwise_fma(w, (v2f){a2.w, a2.w}, acc[11]);
        }
    }

    // acc[0..8] = M row-major, acc[9..11] = T; component .x = vertex A, .y = B
    if (validA) {
        float o0 = acc[0].x*xA0 + acc[1].x*xA1 + acc[2].x*xA2 + acc[9].x;
        float o1 = acc[3].x*xA0 + acc[4].x*xA1 + acc[5].x*xA2 + acc[10].x;
        float o2 = acc[6].x*xA0 + acc[7].x*xA1 + acc[8].x*xA2 + acc[11].x;
        float* op = out + ((size_t)b * Vv + vA) * 3;
        op[0] = o0; op[1] = o1; op[2] = o2;
    }
    if (validB) {
        float o0 = acc[0].y*xB0 + acc[1].y*xB1 + acc[2].y*xB2 + acc[9].y;
        float o1 = acc[3].y*xB0 + acc[4].y*xB1 + acc[5].y*xB2 + acc[10].y;
        float o2 = acc[6].y*xB0 + acc[7].y*xB1 + acc[8].y*xB2 + acc[11].y;
        float* op = out + ((size_t)b * Vv + vB) * 3;
        op[0] = o0; op[1] = o1; op[2] = o2;
    }
}

extern "C" void kernel_launch(void* const* d_in, const int* in_sizes, int n_in,
                              void* d_out, int out_size, void* d_ws, size_t ws_size,
                              hipStream_t stream) {
    const float* X   = (const float*)d_in[0];  // (B,V,3) fp32
    const float* Vn  = (const float*)d_in[1];  // (B,C,3) fp32
    const float* r6  = (const float*)d_in[2];  // (B,C,6) fp32
    const float* W   = (const float*)d_in[3];  // (V,C)   fp32
    const int*   idx = (const int*)d_in[4];    // (C,)    int32
    float* out = (float*)d_out;                // (B,V,3) fp32
    float* A = (float*)d_ws;                   // B*C*12 floats = 30720 B

    precompute_A<<<(Bv * Cv + 255) / 256, 256, 0, stream>>>(X, Vn, r6, idx, A);
    deform_main<<<(Vv + 127) / 128, 256, 0, stream>>>(X, W, A, out);
}